// Round 12
// baseline (4983.246 us; speedup 1.0000x reference)
//
#include <hip/hip_runtime.h>
#include <math.h>

#define BATCH 10
#define HID 128
#define OUT 7
#define MAXLEN 2048
#define NG (4*HID)          // 512 gates
#define NT 1024             // 2 threads per gate (k-split halves)
#define WOUT_STRIDE 132
#define LOGBUF 256
#define OFF_STATE ((size_t)BATCH * MAXLEN * OUT)

__device__ __forceinline__ float sigmoidf_(float x) { return 1.0f / (1.0f + expf(-x)); }

__global__
__attribute__((amdgpu_flat_work_group_size(NT, NT), amdgpu_waves_per_eu(4, 4)))
void decoder_rnn_kernel(const float* __restrict__ h0,
                        const float* __restrict__ c0,
                        const float* __restrict__ tonehot,   // (MAXLEN+1, 1, OUT)
                        const void*  __restrict__ tf_raw,    // bool mask, int8 or int32
                        const float* __restrict__ Wih,       // (4H, OUT)
                        const float* __restrict__ Whh,       // (4H, H)
                        const float* __restrict__ bih,
                        const float* __restrict__ bhh,
                        const float* __restrict__ Wout,      // (OUT, H)
                        const float* __restrict__ bout,
                        float* __restrict__ out)
{
    // two independent batch chains (A=even, B=odd) interleaved in one block:
    // each chain's serial tail hides under the other chain's dot issue.
    __shared__ __align__(16) float h_lds[2][HID];
    __shared__ float partA_lds[2][NG];
    __shared__ float partB_lds[2][NG];
    __shared__ float Wih_lds[OUT * NG];          // transposed: [x][g]
    __shared__ float Wout_lds[OUT * WOUT_STRIDE];
    __shared__ float bout_lds[8];
    __shared__ float log_lds[2][LOGBUF][OUT];    // staged log-probs per chain
    __shared__ int   tgt_lds[MAXLEN];
    __shared__ unsigned char tf_lds[MAXLEN];
    __shared__ int   xsel_sh[2];
    __shared__ int   tf_byte_mode;

    const int t    = threadIdx.x;     // 0..1023
    const int g    = t & (NG - 1);
    const int half = t >> 9;
    const int lane = t & 63;
    const int wv   = t >> 6;          // wave id 0..15
    const int bA   = 2 * blockIdx.x;
    const int bB   = bA + 1;

    // ---- half-row of W_hh into 64 registers; single opaque pin (R7-proven) ----
    float wf[64];
    {
        const float4* wr = (const float4*)(Whh + (size_t)g * HID + half * 64);
        #pragma unroll
        for (int i = 0; i < 16; i++) {
            float4 v = wr[i];
            wf[4*i+0] = v.x; wf[4*i+1] = v.y; wf[4*i+2] = v.z; wf[4*i+3] = v.w;
        }
    }
#define PIN8(i) asm volatile("" : "+v"(wf[i]), "+v"(wf[i+1]), "+v"(wf[i+2]), "+v"(wf[i+3]), \
                                  "+v"(wf[i+4]), "+v"(wf[i+5]), "+v"(wf[i+6]), "+v"(wf[i+7]))
    PIN8(0); PIN8(8); PIN8(16); PIN8(24);
    PIN8(32); PIN8(40); PIN8(48); PIN8(56);
#undef PIN8

    const float bias_g = (half == 0) ? (bih[g] + bhh[g]) : 0.0f;

    // ---- W_ih transposed into LDS ----
    for (int idx = t; idx < OUT * NG; idx += NT) {
        int x = idx >> 9, gg = idx & (NG - 1);
        Wih_lds[x * NG + gg] = Wih[gg * OUT + x];
    }
    // ---- W_out into LDS, padded ----
    for (int idx = t; idx < OUT * HID; idx += NT) {
        int j = idx / HID, k = idx % HID;
        Wout_lds[j * WOUT_STRIDE + k] = Wout[idx];
    }
    if (t < 8) bout_lds[t] = (t < OUT) ? bout[t] : 0.0f;

    // ---- target indices ----
    for (int s = t; s < MAXLEN; s += NT) {
        const float* row = tonehot + (size_t)(s + 1) * OUT;
        int idx = 0;
        #pragma unroll
        for (int j = 0; j < OUT; j++) if (row[j] > 0.5f) idx = j;
        tgt_lds[s] = idx;
    }

    // ---- tf_mask layout detection ----
    if (t == 0) { tf_byte_mode = 0; xsel_sh[0] = OUT - 1; xsel_sh[1] = OUT - 1; }
    __syncthreads();
    {
        const unsigned char* tb = (const unsigned char*)tf_raw;
        int mis = 0;
        for (int p = t; p < MAXLEN; p += NT)
            if ((p & 3) && tb[p]) mis = 1;
        if (mis) atomicOr(&tf_byte_mode, 1);
    }
    // ---- state init ----
    if (t < HID) { h_lds[0][t] = h0[bA * HID + t]; h_lds[1][t] = h0[bB * HID + t]; }
    float cA = (t < HID) ? c0[bA * HID + t] : 0.0f;
    float cB = (t < HID) ? c0[bB * HID + t] : 0.0f;
    __syncthreads();
    if (tf_byte_mode) {
        const unsigned char* tb = (const unsigned char*)tf_raw;
        for (int s = t; s < MAXLEN; s += NT) tf_lds[s] = (tb[s] != 0);
    } else {
        const int* ti = (const int*)tf_raw;
        for (int s = t; s < MAXLEN; s += NT) tf_lds[s] = (ti[s] != 0);
    }
    __syncthreads();

    // ---- wave 2: cache W_out slice + bias in registers ----
    float woutr[16];
    float boutr = 0.0f;
    const int jc = lane & 7;
    const int sg = lane >> 3;
    if (wv == 2) {
        #pragma unroll
        for (int kk = 0; kk < 16; kk++)
            woutr[kk] = Wout_lds[jc * WOUT_STRIDE + sg * 16 + kk];
        boutr = bout_lds[jc];
    } else {
        #pragma unroll
        for (int kk = 0; kk < 16; kk++) woutr[kk] = 0.0f;
    }

    float* outA = out + (size_t)bA * MAXLEN * OUT;
    float* outB = out + (size_t)bB * MAXLEN * OUT;

#define DOT(ch) do { \
    float hreg_ = h_lds[ch][(half << 6) + lane]; \
    int hi_ = __float_as_int(hreg_); \
    float a0_ = (half == 0) ? bias_g : 0.0f; \
    float a1_ = 0.f, a2_ = 0.f, a3_ = 0.f; \
    _Pragma("unroll") \
    for (int j_ = 0; j_ < 64; j_ += 4) { \
        float s0_ = __int_as_float(__builtin_amdgcn_readlane(hi_, j_)); \
        float s1_ = __int_as_float(__builtin_amdgcn_readlane(hi_, j_ + 1)); \
        float s2_ = __int_as_float(__builtin_amdgcn_readlane(hi_, j_ + 2)); \
        float s3_ = __int_as_float(__builtin_amdgcn_readlane(hi_, j_ + 3)); \
        a0_ += s0_ * wf[j_]; a1_ += s1_ * wf[j_ + 1]; \
        a2_ += s2_ * wf[j_ + 2]; a3_ += s3_ * wf[j_ + 3]; } \
    float acc_ = (a0_ + a1_) + (a2_ + a3_); \
    if (half) partB_lds[ch][g] = acc_; else partA_lds[ch][g] = acc_; \
} while (0)

#define PW(ch, CREG) do { \
    const int xo_ = xsel_sh[ch] * NG; \
    float ri_ = partA_lds[ch][t]         + partB_lds[ch][t]         + Wih_lds[xo_ + t]; \
    float rf_ = partA_lds[ch][HID + t]   + partB_lds[ch][HID + t]   + Wih_lds[xo_ + HID + t]; \
    float rg_ = partA_lds[ch][2*HID + t] + partB_lds[ch][2*HID + t] + Wih_lds[xo_ + 2*HID + t]; \
    float ro_ = partA_lds[ch][3*HID + t] + partB_lds[ch][3*HID + t] + Wih_lds[xo_ + 3*HID + t]; \
    float c2_ = sigmoidf_(rf_) * CREG + sigmoidf_(ri_) * tanhf(rg_); \
    CREG = c2_; \
    h_lds[ch][t] = sigmoidf_(ro_) * tanhf(c2_); \
} while (0)

#define LOGITS(ch, sm1) do { \
    const float4* h4_ = (const float4*)h_lds[ch]; \
    float p_ = 0.f; \
    _Pragma("unroll") \
    for (int q_ = 0; q_ < 4; q_++) { \
        float4 hv_ = h4_[sg * 4 + q_]; \
        p_ += hv_.x * woutr[4*q_+0]; p_ += hv_.y * woutr[4*q_+1]; \
        p_ += hv_.z * woutr[4*q_+2]; p_ += hv_.w * woutr[4*q_+3]; } \
    p_ += __shfl_xor(p_, 8, 64); p_ += __shfl_xor(p_, 16, 64); p_ += __shfl_xor(p_, 32, 64); \
    float logit_ = (jc < OUT) ? (p_ + boutr) : -INFINITY; \
    float mv_ = logit_; int mi_ = jc; \
    _Pragma("unroll") \
    for (int d_ = 1; d_ < 8; d_ <<= 1) { \
        float ov_ = __shfl_xor(mv_, d_, 64); \
        int   oi_ = __shfl_xor(mi_, d_, 64); \
        if (ov_ > mv_ || (ov_ == mv_ && oi_ < mi_)) { mv_ = ov_; mi_ = oi_; } } \
    float e_ = (jc < OUT) ? expf(logit_ - mv_) : 0.0f; \
    float ss_ = e_; \
    _Pragma("unroll") \
    for (int d_ = 1; d_ < 8; d_ <<= 1) ss_ += __shfl_xor(ss_, d_, 64); \
    float lse_ = mv_ + logf(ss_); \
    if (lane < OUT) log_lds[ch][(sm1) & (LOGBUF - 1)][lane] = logit_ - lse_; \
    if (lane == 0)  xsel_sh[ch] = tf_lds[sm1] ? tgt_lds[sm1] : mi_; \
} while (0)

#define FLUSH(ch, base, OUTP) do { \
    for (int i_ = t; i_ < LOGBUF * OUT; i_ += NT) { \
        int st_ = i_ / OUT, j_ = i_ - st_ * OUT; \
        OUTP[(size_t)((base) + st_) * OUT + j_] = log_lds[ch][st_][j_]; \
    } } while (0)

    for (int s = 0; s < MAXLEN; s++) {
        // ---- phase 1: finish B(s-1), logits A(s-1)->xsel_A(s), dot A(s) ----
        if ((s & 255) == 1 && s > 1) FLUSH(1, s - 257, outB);
        if (s > 0 && t < HID) PW(1, cB);
        if (s > 0 && wv == 2) LOGITS(0, s - 1);
        DOT(0);
        __syncthreads();

        // ---- phase 2: finish A(s), logits B(s-1)->xsel_B(s), dot B(s) ----
        if ((s & 255) == 0 && s > 0) FLUSH(0, s - 256, outA);
        if (t < HID) PW(0, cA);
        if (s > 0 && wv == 2) LOGITS(1, s - 1);
        DOT(1);
        __syncthreads();
    }

    // ---- epilogue ----
    if (t < HID) PW(1, cB);                 // B step 2047
    if (wv == 2) LOGITS(0, MAXLEN - 1);     // A logits 2047 (xsel write harmless)
    __syncthreads();
    if (wv == 2) LOGITS(1, MAXLEN - 1);     // B logits 2047
    __syncthreads();
    FLUSH(0, MAXLEN - LOGBUF, outA);
    FLUSH(1, MAXLEN - LOGBUF, outB);

    if (t < HID) {
        out[OFF_STATE + bA * HID + t] = h_lds[0][t];
        out[OFF_STATE + bB * HID + t] = h_lds[1][t];
        out[OFF_STATE + BATCH * HID + bA * HID + t] = cA;
        out[OFF_STATE + BATCH * HID + bB * HID + t] = cB;
    }

#undef DOT
#undef PW
#undef LOGITS
#undef FLUSH
}

extern "C" void kernel_launch(void* const* d_in, const int* in_sizes, int n_in,
                              void* d_out, int out_size, void* d_ws, size_t ws_size,
                              hipStream_t stream) {
    const float* h0    = (const float*)d_in[0];
    const float* c0    = (const float*)d_in[1];
    const float* toh   = (const float*)d_in[2];
    const void*  tfm   = (const void*) d_in[3];
    const float* Wih   = (const float*)d_in[4];
    const float* Whh   = (const float*)d_in[5];
    const float* bih   = (const float*)d_in[6];
    const float* bhh   = (const float*)d_in[7];
    const float* Wout  = (const float*)d_in[8];
    const float* bout  = (const float*)d_in[9];
    float* out = (float*)d_out;

    decoder_rnn_kernel<<<dim3(BATCH / 2), dim3(NT), 0, stream>>>(
        h0, c0, toh, tfm, Wih, Whh, bih, bhh, Wout, bout, out);
}

// Round 13
// 3053.931 us; speedup vs baseline: 1.6317x; 1.6317x over previous
//
#include <hip/hip_runtime.h>
#include <math.h>

#define BATCH 10
#define HID 128
#define OUT 7
#define MAXLEN 2048
#define NG (4*HID)          // 512 gates
#define NT 1024             // threads: 2 per gate (k-split halves)
#define WOUT_STRIDE 132     // pad 128 -> 132 to avoid LDS bank conflicts
#define LOGBUF 256          // raw-logit staging depth (flush every 256 steps)

__device__ __forceinline__ float sigmoidf_(float x) { return 1.0f / (1.0f + expf(-x)); }

__global__
__attribute__((amdgpu_flat_work_group_size(NT, NT), amdgpu_waves_per_eu(4, 4)))
void decoder_rnn_kernel(const float* __restrict__ h0,
                        const float* __restrict__ c0,
                        const float* __restrict__ tonehot,   // (MAXLEN+1, 1, OUT)
                        const void*  __restrict__ tf_raw,    // bool mask, int8 or int32
                        const float* __restrict__ Wih,       // (4H, OUT)
                        const float* __restrict__ Whh,       // (4H, H)
                        const float* __restrict__ bih,
                        const float* __restrict__ bhh,
                        const float* __restrict__ Wout,      // (OUT, H)
                        const float* __restrict__ bout,
                        float* __restrict__ out)
{
    __shared__ __align__(16) float h_lds[HID];
    __shared__ float part_lds[NG];               // half1 partial dots
    __shared__ float gates_lds[NG];              // transformed gates
    __shared__ float Wih_lds[OUT * NG];          // transposed: [x][g]
    __shared__ float Wout_lds[OUT * WOUT_STRIDE];
    __shared__ float bout_lds[8];
    __shared__ float log_lds[LOGBUF][OUT];       // staged RAW logits
    __shared__ int   tgt_lds[MAXLEN];
    __shared__ unsigned char tf_lds[MAXLEN];
    __shared__ int   xsel_sh;
    __shared__ int   tf_byte_mode;

    const int t    = threadIdx.x;     // 0..1023
    const int g    = t & (NG - 1);    // gate index 0..511
    const int half = t >> 9;          // k-half: 0 -> k 0..63, 1 -> k 64..127
    const int lane = t & 63;
    const int b    = blockIdx.x;      // batch chain

    // ---- half-row of W_hh into 64 registers; single opaque pin ----
    // With woutr[16] removed (see logits below), working set ~80 regs at the
    // 128-reg budget (waves_per_eu 4): goal is ARCH-VGPR residency of wf so
    // the MAC is readlane+fmac (2 instr), not readlane+accvgpr_read+fmac (3).
    float wf[64];
    {
        const float4* wr = (const float4*)(Whh + (size_t)g * HID + half * 64);
        #pragma unroll
        for (int i = 0; i < 16; i++) {
            float4 v = wr[i];
            wf[4*i+0] = v.x; wf[4*i+1] = v.y; wf[4*i+2] = v.z; wf[4*i+3] = v.w;
        }
    }
#define PIN8(i) asm volatile("" : "+v"(wf[i]), "+v"(wf[i+1]), "+v"(wf[i+2]), "+v"(wf[i+3]), \
                                  "+v"(wf[i+4]), "+v"(wf[i+5]), "+v"(wf[i+6]), "+v"(wf[i+7]))
    PIN8(0); PIN8(8); PIN8(16); PIN8(24);
    PIN8(32); PIN8(40); PIN8(48); PIN8(56);
#undef PIN8

    const float bias_g   = (half == 0) ? (bih[g] + bhh[g]) : 0.0f;
    const bool  is_gcell = ((g >> 7) == 2);      // gates 256..383 use tanh

    // ---- W_ih transposed into LDS: Wih_lds[x*NG + gg] ----
    for (int idx = t; idx < OUT * NG; idx += NT) {
        int x = idx >> 9, gg = idx & (NG - 1);
        Wih_lds[x * NG + gg] = Wih[gg * OUT + x];
    }

    // ---- W_out into LDS with padded stride ----
    for (int idx = t; idx < OUT * HID; idx += NT) {
        int j = idx / HID, k = idx % HID;
        Wout_lds[j * WOUT_STRIDE + k] = Wout[idx];
    }
    if (t < 8) bout_lds[t] = (t < OUT) ? bout[t] : 0.0f;

    // ---- target indices: tgt_next[s] = argmax(onehot[s+1]) ----
    for (int s = t; s < MAXLEN; s += NT) {
        const float* row = tonehot + (size_t)(s + 1) * OUT;
        int idx = 0;
        #pragma unroll
        for (int j = 0; j < OUT; j++) if (row[j] > 0.5f) idx = j;
        tgt_lds[s] = idx;
    }

    // ---- tf_mask layout detection (int8 bool vs int32) ----
    if (t == 0) { tf_byte_mode = 0; xsel_sh = OUT - 1; }  // x0 = one-hot at OUT-1
    __syncthreads();
    {
        const unsigned char* tb = (const unsigned char*)tf_raw;
        int mis = 0;
        for (int p = t; p < MAXLEN; p += NT)          // first 2048 bytes: safe in both layouts
            if ((p & 3) && tb[p]) mis = 1;
        if (mis) atomicOr(&tf_byte_mode, 1);
    }
    // ---- state init ----
    if (t < HID) h_lds[t] = h0[b * HID + t];
    float c_reg = (t < HID) ? c0[b * HID + t] : 0.0f;
    __syncthreads();
    if (tf_byte_mode) {
        const unsigned char* tb = (const unsigned char*)tf_raw;
        for (int s = t; s < MAXLEN; s += NT) tf_lds[s] = (tb[s] != 0);
    } else {
        const int* ti = (const int*)tf_raw;
        for (int s = t; s < MAXLEN; s += NT) tf_lds[s] = (ti[s] != 0);
    }
    __syncthreads();   // setup LDS (incl. Wout/bout) + h0 ready

    const int j_cls = t & 7;        // output class (7 is a dummy), valid for t<64
    const int seg   = t >> 3;       // k-segment (16 wide), valid for t<64
    const float boutr = (t < 64) ? bout_lds[j_cls] : 0.0f;   // 1 reg, not 16

    float* outlp = out + (size_t)b * MAXLEN * OUT;

    for (int s = 0; s < MAXLEN; s++) {
        // entry invariant: h_lds = h_{s} input (== h2 of step s-1), barrier done.

        // ---- gate half-dot via readlane broadcast (all 16 waves) ----
        float hreg = h_lds[(half << 6) + lane];
        int   hi   = __float_as_int(hreg);
        float a0 = (half == 0) ? bias_g : 0.0f;
        float a1 = 0.f, a2 = 0.f, a3 = 0.f;
        #pragma unroll
        for (int j = 0; j < 64; j += 4) {
            float s0 = __int_as_float(__builtin_amdgcn_readlane(hi, j));
            float s1 = __int_as_float(__builtin_amdgcn_readlane(hi, j + 1));
            float s2 = __int_as_float(__builtin_amdgcn_readlane(hi, j + 2));
            float s3 = __int_as_float(__builtin_amdgcn_readlane(hi, j + 3));
            a0 += s0 * wf[j];
            a1 += s1 * wf[j + 1];
            a2 += s2 * wf[j + 2];
            a3 += s3 * wf[j + 3];
        }
        float acc = (a0 + a1) + (a2 + a3);
        if (half) part_lds[g] = acc;

        // ---- wave 0 concurrently: RAW logits(s-1) + argmax -> xsel(s) ----
        // log-softmax deferred to the bulk flush (only argmax is critical).
        if (s > 0 && t < 64) {
            const float4* h4 = (const float4*)h_lds;
            const float4* w4 = (const float4*)&Wout_lds[j_cls * WOUT_STRIDE + seg * 16];
            float p = 0.f;
            #pragma unroll
            for (int q = 0; q < 4; q++) {
                float4 hv = h4[seg * 4 + q];
                float4 wv = w4[q];
                p += hv.x * wv.x + hv.y * wv.y + hv.z * wv.z + hv.w * wv.w;
            }
            p += __shfl_xor(p, 8, 64);
            p += __shfl_xor(p, 16, 64);
            p += __shfl_xor(p, 32, 64);
            float logit = (j_cls < OUT) ? (p + boutr) : -INFINITY;

            float mv = logit; int mi = j_cls;
            #pragma unroll
            for (int d = 1; d < 8; d <<= 1) {
                float ov = __shfl_xor(mv, d, 64);
                int   oi = __shfl_xor(mi, d, 64);
                if (ov > mv || (ov == mv && oi < mi)) { mv = ov; mi = oi; }
            }
            if (t < OUT) log_lds[(s - 1) & (LOGBUF - 1)][t] = logit;
            if (t == 0)  xsel_sh = tf_lds[s - 1] ? tgt_lds[s - 1] : mi;
        }
        __syncthreads();   // A: partials + xsel + raw-logit slot (s-1) ready

        // ---- bulk flush every 256 steps: log-softmax + store, 1 row/thread ----
        if ((s & (LOGBUF - 1)) == 0 && s > 0 && t < LOGBUF) {
            const int base = s - LOGBUF;
            float v[OUT];
            #pragma unroll
            for (int j = 0; j < OUT; j++) v[j] = log_lds[t][j];
            float mx = v[0];
            #pragma unroll
            for (int j = 1; j < OUT; j++) mx = fmaxf(mx, v[j]);
            float sum = 0.f;
            #pragma unroll
            for (int j = 0; j < OUT; j++) sum += expf(v[j] - mx);
            float lse = mx + logf(sum);
            float* dst = outlp + (size_t)(base + t) * OUT;
            #pragma unroll
            for (int j = 0; j < OUT; j++) dst[j] = v[j] - lse;
        }

        // ---- combine halves + transcendental (half0 threads own gate g) ----
        if (half == 0) {
            float raw = acc + part_lds[g] + Wih_lds[xsel_sh * NG + g];
            gates_lds[g] = is_gcell ? tanhf(raw) : sigmoidf_(raw);
        }
        __syncthreads();   // B: transformed gates ready

        // ---- LSTM combine (threads 0..127), c stays in register ----
        if (t < HID) {
            float ti_ = gates_lds[t];
            float tf_ = gates_lds[HID + t];
            float tg_ = gates_lds[2 * HID + t];
            float to_ = gates_lds[3 * HID + t];
            float c2 = tf_ * c_reg + ti_ * tg_;
            c_reg = c2;
            h_lds[t] = to_ * tanhf(c2);
        }
        __syncthreads();   // C: h2 ready
    }

    // ---- epilogue: raw logits for final step -> slot 255, then final flush ----
    if (t < 64) {
        const float4* h4 = (const float4*)h_lds;
        const float4* w4 = (const float4*)&Wout_lds[j_cls * WOUT_STRIDE + seg * 16];
        float p = 0.f;
        #pragma unroll
        for (int q = 0; q < 4; q++) {
            float4 hv = h4[seg * 4 + q];
            float4 wv = w4[q];
            p += hv.x * wv.x + hv.y * wv.y + hv.z * wv.z + hv.w * wv.w;
        }
        p += __shfl_xor(p, 8, 64);
        p += __shfl_xor(p, 16, 64);
        p += __shfl_xor(p, 32, 64);
        float logit = (j_cls < OUT) ? (p + boutr) : -INFINITY;
        if (t < OUT) log_lds[(MAXLEN - 1) & (LOGBUF - 1)][t] = logit;
    }
    __syncthreads();   // slot 255 (step 2047) ready

    if (t < LOGBUF) {  // final flush with deferred log-softmax: steps 1792..2047
        const int base = MAXLEN - LOGBUF;
        float v[OUT];
        #pragma unroll
        for (int j = 0; j < OUT; j++) v[j] = log_lds[t][j];
        float mx = v[0];
        #pragma unroll
        for (int j = 1; j < OUT; j++) mx = fmaxf(mx, v[j]);
        float sum = 0.f;
        #pragma unroll
        for (int j = 0; j < OUT; j++) sum += expf(v[j] - mx);
        float lse = mx + logf(sum);
        float* dst = outlp + (size_t)(base + t) * OUT;
        #pragma unroll
        for (int j = 0; j < OUT; j++) dst[j] = v[j] - lse;
    }

    if (t < HID) {
        out[(size_t)BATCH * MAXLEN * OUT + b * HID + t] = h_lds[t];                 // hT
        out[(size_t)BATCH * MAXLEN * OUT + BATCH * HID + b * HID + t] = c_reg;      // cT
    }
}

extern "C" void kernel_launch(void* const* d_in, const int* in_sizes, int n_in,
                              void* d_out, int out_size, void* d_ws, size_t ws_size,
                              hipStream_t stream) {
    const float* h0    = (const float*)d_in[0];
    const float* c0    = (const float*)d_in[1];
    const float* toh   = (const float*)d_in[2];
    const void*  tfm   = (const void*) d_in[3];
    const float* Wih   = (const float*)d_in[4];
    const float* Whh   = (const float*)d_in[5];
    const float* bih   = (const float*)d_in[6];
    const float* bhh   = (const float*)d_in[7];
    const float* Wout  = (const float*)d_in[8];
    const float* bout  = (const float*)d_in[9];
    float* out = (float*)d_out;

    decoder_rnn_kernel<<<dim3(BATCH), dim3(NT), 0, stream>>>(
        h0, c0, toh, tfm, Wih, Whh, bih, bhh, Wout, bout, out);
}